// Round 13
// baseline (170.117 us; speedup 1.0000x reference)
//
#include <hip/hip_runtime.h>
#include <hip/hip_bf16.h>

// B=2, T=2048, C=1024, H=16, D=64
// qkv = x@w_attn + b_attn ; causal attention ; out = y@w_proj + b_proj
// R20: attn split-K (flash-decoding). Even with LPT+backfill (R19, -3.7us)
//      the makespan floor is the LONGEST block (qb=31: 32 iters ~21us) vs
//      16.5-iter mean slot load. Static-max softmax => partials are plain
//      sums: combine = (O1+O2)/(l1+l2), trivial add. qb>=16 blocks split
//      into 2 halves of <=16 tiles -> max block 16 iters; grid 1536, LDS
//      back to 40KB (Pl 8KB) -> 4 blk/CU, 512-block backfill, LPT order
//      (len-16 first). Split epilogue: raw f32 O-fragments (float4) + l
//      to ws partials (16MB @48MB, 0.25MB @64MB); combine kernel (512 blk)
//      adds+normalizes+stores split half of Y. Unsplit = R18 epilogue.
//      Keep pk2t inner pack. qkv/proj/prep byte-identical to R19.

typedef __attribute__((ext_vector_type(8))) short short8x;   // 8 bf16 (A/B frag)
typedef __attribute__((ext_vector_type(4))) float float4x;   // C/D frag
typedef __attribute__((ext_vector_type(4))) unsigned short ushort4x;
typedef __attribute__((ext_vector_type(2))) unsigned int uint2x;

#define MFMA_BF16 __builtin_amdgcn_mfma_f32_16x16x32_bf16

typedef const __attribute__((address_space(1))) void gvoid_t;
typedef __attribute__((address_space(3))) void lvoid_t;
#define GLOAD_LDS16(g, l) __builtin_amdgcn_global_load_lds((gvoid_t*)(g), (lvoid_t*)(l), 16, 0, 0)

__device__ __forceinline__ unsigned short f2b(float f) {
    unsigned int u = __float_as_uint(f);
    u = (u + 0x7FFFu + ((u >> 16) & 1u)) >> 16;
    return (unsigned short)u;
}
// rounded pack (round-half-up): lo16 = bf16(a), hi16 = bf16(b). 3 VALU.
__device__ __forceinline__ unsigned int pk2(float a, float b) {
    return __builtin_amdgcn_perm(__float_as_uint(b) + 0x8000u,
                                 __float_as_uint(a) + 0x8000u, 0x07060302u);
}
// truncating pack: lo16 = trunc_bf16(a), hi16 = trunc_bf16(b). 1 VALU.
// Safe for e = exp2(S) >= 0; bias cancels in P/l normalization.
__device__ __forceinline__ unsigned int pk2t(float a, float b) {
    return __builtin_amdgcn_perm(__float_as_uint(b),
                                 __float_as_uint(a), 0x07060302u);
}

// Stage rows [w0,w0+32) of a 64-short-wide tile from global (row stride rs
// shorts) into LDS (stride 64), source-XOR-swizzled: phys chunk c of row R
// holds logical chunk c^(R&7). 4 DMA instrs, 8 rows each.
__device__ __forceinline__ void stage32(const unsigned short* g, size_t rs,
                                        short* ldst, int w0, int lane) {
    const int r8 = lane >> 3;
    const int sc = ((lane & 7) ^ r8) * 8;
#pragma unroll
    for (int q = 0; q < 4; q++) {
        GLOAD_LDS16(g + (size_t)(w0 + q * 8 + r8) * rs + sc,
                    ldst + (w0 + q * 8) * 64);
    }
}

// ---------------------------------------------------------------------------
// prep: blocks 0..4095 cast x (f32->bf16, float4); blocks 4096..8191
// transpose+cast w_attn (96 col-blocks) / w_proj (32 col-blocks).
// ---------------------------------------------------------------------------
__global__ __launch_bounds__(256) void prep(const float* __restrict__ x,
                                            unsigned short* __restrict__ xb,
                                            const float* __restrict__ wa,
                                            unsigned short* __restrict__ waT,
                                            const float* __restrict__ wp,
                                            unsigned short* __restrict__ wpT) {
    __shared__ float tile[32][33];
    const int blk = blockIdx.x;
    if (blk < 4096) {
        int i = blk * 256 + threadIdx.x;
        float4 v = ((const float4*)x)[i];
        ushort4x o = { f2b(v.x), f2b(v.y), f2b(v.z), f2b(v.w) };
        ((ushort4x*)xb)[i] = o;
        return;
    }
    int idx = blk - 4096;
    int bx = idx & 127;   // 0..127
    int by = idx >> 7;    // 0..31
    const float* in;
    unsigned short* outp;
    int cols;
    if (bx < 96) { in = wa; outp = waT; cols = 3072; }
    else         { in = wp; outp = wpT; cols = 1024; bx -= 96; }
    const int tx = threadIdx.x & 31, ty = threadIdx.x >> 5;
    const int cbase = bx * 32, rbase = by * 32;
    int c = cbase + tx;
    for (int j = 0; j < 32; j += 8)
        tile[ty + j][tx] = in[(size_t)(rbase + ty + j) * cols + c];
    __syncthreads();
    int rr = rbase + tx;
    for (int j = 0; j < 32; j += 8) {
        int cc = cbase + ty + j;
        outp[(size_t)cc * 1024 + rr] = f2b(tile[tx][ty + j]);
    }
}

// ---------------------------------------------------------------------------
// QKV GEMM main loop (R14): compile-time operand order, BK=64 single-buffer.
// SWAP=true computes C^T fragments (lane holds 4 consecutive C columns).
// ---------------------------------------------------------------------------
template <bool SWAP>
__device__ __forceinline__ void qkv_mainloop(const unsigned short* Ag,
                                             const unsigned short* Bg,
                                             short* lA, short* lB,
                                             float4x (&acc)[4][4],
                                             int wave, int lane, int wr, int wc,
                                             int quad, int l16, int sw) {
    const int K = 1024;
    for (int kk = 0; kk < K; kk += 64) {
        stage32(Ag + kk, K, lA, wave * 32, lane);
        stage32(Bg + kk, K, lB, wave * 32, lane);
        __syncthreads();

#pragma unroll
        for (int kk2 = 0; kk2 < 2; kk2++) {
            short8x a[4], b[4];
#pragma unroll
            for (int i = 0; i < 4; i++)
                a[i] = *(const short8x*)&lA[(wr * 64 + i * 16 + l16) * 64 +
                                            ((kk2 * 4 + quad) ^ sw) * 8];
#pragma unroll
            for (int j = 0; j < 4; j++)
                b[j] = *(const short8x*)&lB[(wc * 64 + j * 16 + l16) * 64 +
                                            ((kk2 * 4 + quad) ^ sw) * 8];
#pragma unroll
            for (int i = 0; i < 4; i++)
#pragma unroll
                for (int j = 0; j < 4; j++)
                    acc[i][j] = SWAP ? MFMA_BF16(b[j], a[i], acc[i][j], 0, 0, 0)
                                     : MFMA_BF16(a[i], b[j], acc[i][j], 0, 0, 0);
        }
        __syncthreads();
    }
}

// ---------------------------------------------------------------------------
// QKV GEMM: [4096,3072] = xb[4096,1024] @ waT[3072,1024]^T + b_attn
// 128x128 tile, 4 waves 2x2, BK=64, single-buffered swizzled DMA staging.
// Q/K blocks (x<16): SWAP mainloop -> packed 8B stores + float4 bias.
// V blocks: standard orientation -> VT[bh][d][t] via LDS transpose.
// ---------------------------------------------------------------------------
__global__ __launch_bounds__(256, 4) void gemm_qkv(const unsigned short* __restrict__ A,
                                                   const unsigned short* __restrict__ BT,
                                                   const float* __restrict__ bias,
                                                   unsigned short* __restrict__ QK,
                                                   unsigned short* __restrict__ VTg) {
    __shared__ union {
        struct { short A[128 * 64]; short B[128 * 64]; } s;   // 32 KB
        short vt[4][64 * 80];                                  // 40 KB
    } lds;

    const int K = 1024;
    const int lane = threadIdx.x & 63;
    const int wave = threadIdx.x >> 6;
    const int quad = lane >> 4;
    const int l16  = lane & 15;
    const int sw   = l16 & 7;

    const int rblk = blockIdx.y * 128;
    const int cblk = blockIdx.x * 128;
    const int wr = wave >> 1, wc = wave & 1;
    const bool qk = (blockIdx.x < 16);   // blocks 0..15 pure Q/K, 16..23 pure V

    float4x acc[4][4] = {};

    const unsigned short* Ag = A  + (size_t)rblk * K;
    const unsigned short* Bg = BT + (size_t)cblk * K;

    if (qk) qkv_mainloop<true >(Ag, Bg, lds.s.A, lds.s.B, acc, wave, lane, wr, wc, quad, l16, sw);
    else    qkv_mainloop<false>(Ag, Bg, lds.s.A, lds.s.B, acc, wave, lane, wr, wc, quad, l16, sw);

    const int rbase = rblk + wr * 64;
    const int cbase = cblk + wc * 64;

    if (qk) {
        // swapped layout: lane (l16,quad) reg r holds C[rbase+i*16+l16]
        //                                             [cbase+j*16+quad*4+r]
        const float sc = (blockIdx.x < 8) ? 0.18033688f : 1.0f;  // log2(e)/8 | 1
#pragma unroll
        for (int i = 0; i < 4; i++) {
            const int r = rbase + i * 16 + l16;
#pragma unroll
            for (int j = 0; j < 4; j++) {
                const int c = cbase + j * 16 + quad * 4;
                float4 bv = *(const float4*)&bias[c];
                uint2x p = { pk2((acc[i][j][0] + bv.x) * sc, (acc[i][j][1] + bv.y) * sc),
                             pk2((acc[i][j][2] + bv.z) * sc, (acc[i][j][3] + bv.w) * sc) };
                *(uint2x*)&QK[(size_t)r * 2048 + c] = p;
            }
        }
    } else {
#pragma unroll
        for (int i = 0; i < 4; i++) {
#pragma unroll
            for (int j = 0; j < 4; j++) {
                int c = cbase + j * 16 + l16;
                float bv = bias[c];
                uint2x p = { pk2(acc[i][j][0] + bv, acc[i][j][1] + bv),
                             pk2(acc[i][j][2] + bv, acc[i][j][3] + bv) };
                *(uint2x*)&lds.vt[wave][(j * 16 + l16) * 80 + i * 16 + quad * 4] = p;
            }
        }
        const int h   = (cbase - 2048) >> 6;
        const int hb  = (rbase >> 11) * 16 + h;
        const int tb0 = rbase & 2047;
#pragma unroll
        for (int p = 0; p < 8; p++) {
            int dd   = p * 8 + (lane >> 3);
            int toff = (lane & 7) * 8;
            short8x vv = *(const short8x*)&lds.vt[wave][dd * 80 + toff];
            *(short8x*)&VTg[((size_t)(hb * 64 + dd)) * 2048 + tb0 + toff] = vv;
        }
    }
}

// ---------------------------------------------------------------------------
// Proj GEMM: out[4096,1024] = yb @ wpT^T + b_proj (fp32).
// 64(M) x 128(N) tile, 4 waves side-by-side in N (64x32 each): per wave
// 16 MFMA + 12 ds_reads per 64-K step. BK=64 single-buffered, 24 KB LDS.
// grid (8, 64) = 512 blocks = 2/CU.
// ---------------------------------------------------------------------------
__global__ __launch_bounds__(256) void gemm_proj(const unsigned short* __restrict__ A,
                                                 const unsigned short* __restrict__ BT,
                                                 const float* __restrict__ bias,
                                                 float* __restrict__ out) {
    __shared__ struct { short A[64 * 64]; short B[128 * 64]; } lds;  // 24 KB

    const int K = 1024, N = 1024;
    const int lane = threadIdx.x & 63;
    const int wave = threadIdx.x >> 6;
    const int quad = lane >> 4;
    const int l16  = lane & 15;
    const int sw   = l16 & 7;

    const int rblk = blockIdx.y * 64;
    const int cblk = blockIdx.x * 128;

    float4x acc[4][2] = {};

    const unsigned short* Ag = A  + (size_t)rblk * K;
    const unsigned short* Bg = BT + (size_t)cblk * K;

    for (int kk = 0; kk < K; kk += 64) {
        if (wave < 2) {
            stage32(Ag + kk, K, lds.A, wave * 32, lane);
        } else {
            stage32(Bg + kk, K, lds.B, (wave - 2) * 64, lane);
            stage32(Bg + kk, K, lds.B, (wave - 2) * 64 + 32, lane);
        }
        __syncthreads();

#pragma unroll
        for (int kk2 = 0; kk2 < 2; kk2++) {
            short8x b[2];
#pragma unroll
            for (int j = 0; j < 2; j++)
                b[j] = *(const short8x*)&lds.B[(wave * 32 + j * 16 + l16) * 64 +
                                               ((kk2 * 4 + quad) ^ sw) * 8];
#pragma unroll
            for (int i = 0; i < 4; i++) {
                short8x a = *(const short8x*)&lds.A[(i * 16 + l16) * 64 +
                                                    ((kk2 * 4 + quad) ^ sw) * 8];
#pragma unroll
                for (int j = 0; j < 2; j++)
                    acc[i][j] = MFMA_BF16(a, b[j], acc[i][j], 0, 0, 0);
            }
        }
        __syncthreads();
    }

#pragma unroll
    for (int j = 0; j < 2; j++) {
        const int c = cblk + wave * 32 + j * 16 + l16;
        const float bv = bias[c];
#pragma unroll
        for (int i = 0; i < 4; i++) {
#pragma unroll
            for (int reg = 0; reg < 4; reg++) {
                int r = rblk + i * 16 + quad * 4 + reg;
                out[(size_t)r * N + c] = acc[i][j][reg] + bv;
            }
        }
    }
}

// ---------------------------------------------------------------------------
// Flash attention (causal), S^T = K*Q^T, static-max base-2 softmax.
// QK [4096][2048] bf16 (Q pre-scaled log2e/8 | K), VT [bh][64][2048] bf16.
// Block = 64 q-rows, 4 waves x 16 rows; 64-key tiles dbuf via swizzled DMA.
// R20 split-K: qb>=16 handled by TWO blocks (tiles [0,16) and [16,qb+1)),
// writing unnormalized f32 O + l partials; combine kernel merges. Max
// block length = 16 iters. Grid 1536, LPT-ordered (len-16 first), LDS
// 40KB -> 4 blk/CU, 512-block backfill. Unsplit (qb<16): R18 epilogue.
// ---------------------------------------------------------------------------
__global__ __launch_bounds__(256) void attn_kernel(const unsigned short* __restrict__ QK,
                                                   const unsigned short* __restrict__ VT,
                                                   unsigned short* __restrict__ Y,
                                                   float* __restrict__ pO,
                                                   float* __restrict__ pL) {
    __shared__ __attribute__((aligned(16))) short Kl[2][64 * 64];  // 16 KB
    __shared__ __attribute__((aligned(16))) short Vl[2][64 * 64];  // 16 KB
    __shared__ __attribute__((aligned(16))) short Pl[4][16 * 64];  //  8 KB

    const int tid  = threadIdx.x;
    const int lane = tid & 63;
    const int wave = tid >> 6;
    const int quad = lane >> 4;
    const int l16  = lane & 15;
    const int sw   = l16 & 7;

    // LPT decode: bid -> (qb, bh, kb0, nt, split, half). Lengths descend
    // with bid: 576 len-16 blocks first, then 64 per length 15..1.
    const int bid = blockIdx.x;
    int qb, bh, kb0, nt, half;
    bool split;
    if (bid < 512) {        // first halves of qb>=16 (len 16)
        qb = 16 + (bid >> 5); bh = bid & 31; kb0 = 0;    nt = 16; split = true;  half = 0;
    } else if (bid < 544) { // qb=15 unsplit (len 16)
        qb = 15;             bh = bid & 31; kb0 = 0;    nt = 16; split = false; half = 0;
    } else if (bid < 576) { // second half of qb=31 (len 16)
        qb = 31;             bh = bid & 31; kb0 = 1024; nt = 16; split = true;  half = 1;
    } else {
        const int g = (bid - 576) >> 6;   // 0..14
        const int r = (bid - 576) & 63;
        const int L = 15 - g;             // 15..1
        bh = r & 31;
        if (r < 32) { qb = L - 1;  kb0 = 0;    nt = L; split = false; half = 0; }
        else        { qb = L + 15; kb0 = 1024; nt = L; split = true;  half = 1; }
    }
    const int b = bh >> 4, h = bh & 15;

    const unsigned short* Qp = QK + ((size_t)b * 2048) * 2048 + h * 64;
    const unsigned short* Kp = Qp + 1024;
    const unsigned short* Vp = VT + (size_t)bh * 64 * 2048;

    const int qbase = qb * 64 + wave * 16;           // 16 q-rows per wave

    short8x aq[2];
#pragma unroll
    for (int kk = 0; kk < 2; kk++)
        aq[kk] = *(const short8x*)(Qp + (size_t)(qbase + l16) * 2048 + kk * 32 + quad * 8);

    // bf16 1.0 fragment for the denominator MFMA
    const short ONE = (short)0x3F80;
    const short8x ones = { ONE, ONE, ONE, ONE, ONE, ONE, ONE, ONE };

    // prologue: stage tile kb0 into buf 0
    if (wave < 2) stage32(Kp + (size_t)kb0 * 2048, 2048, Kl[0], wave * 32, lane);
    else          stage32(Vp + kb0, 2048, Vl[0], (wave - 2) * 32, lane);
    __syncthreads();

    float4x lacc = {};
    float4x O[4] = {};

    for (int it = 0; it < nt; it++) {
        const int kb = kb0 + it * 64;
        const short* Kc = Kl[it & 1];
        const short* Vc = Vl[it & 1];

        if (it + 1 < nt) {
            const int kb2 = kb + 64;
            if (wave < 2) stage32(Kp + (size_t)kb2 * 2048, 2048, Kl[(it + 1) & 1], wave * 32, lane);
            else          stage32(Vp + kb2, 2048, Vl[(it + 1) & 1], (wave - 2) * 32, lane);
        }

        float4x S[4];
#pragma unroll
        for (int t = 0; t < 4; t++) {
            short8x kf0 = *(const short8x*)&Kc[(t * 16 + l16) * 64 + ((quad) ^ sw) * 8];
            short8x kf1 = *(const short8x*)&Kc[(t * 16 + l16) * 64 + ((4 + quad) ^ sw) * 8];
            S[t] = (float4x){0.f, 0.f, 0.f, 0.f};
            S[t] = MFMA_BF16(kf0, aq[0], S[t], 0, 0, 0);
            S[t] = MFMA_BF16(kf1, aq[1], S[t], 0, 0, 0);
        }

        if (kb + 64 > qbase) {
            int q = qbase + l16;
#pragma unroll
            for (int t = 0; t < 4; t++)
#pragma unroll
                for (int reg = 0; reg < 4; reg++)
                    if (kb + t * 16 + quad * 4 + reg > q) S[t][reg] = -1e38f;
        }

#pragma unroll
        for (int t = 0; t < 4; t++) {
            float e0 = __builtin_amdgcn_exp2f(S[t][0]);
            float e1 = __builtin_amdgcn_exp2f(S[t][1]);
            float e2 = __builtin_amdgcn_exp2f(S[t][2]);
            float e3 = __builtin_amdgcn_exp2f(S[t][3]);
            uint2x p = { pk2t(e0, e1), pk2t(e2, e3) };
            *(uint2x*)&Pl[wave][l16 * 64 + ((2 * t + (quad >> 1)) ^ sw) * 8 + (quad & 1) * 4] = p;
        }

#pragma unroll
        for (int kc = 0; kc < 2; kc++) {
            short8x bp = *(const short8x*)&Pl[wave][l16 * 64 + ((4 * kc + quad) ^ sw) * 8];
            lacc = MFMA_BF16(ones, bp, lacc, 0, 0, 0);
#pragma unroll
            for (int dt = 0; dt < 4; dt++) {
                short8x vf = *(const short8x*)&Vc[(dt * 16 + l16) * 64 + ((kc * 4 + quad) ^ sw) * 8];
                O[dt] = MFMA_BF16(vf, bp, O[dt], 0, 0, 0);
            }
        }
        __syncthreads();
    }

    if (split) {
        // write unnormalized partials: pO[slot][ql*64 + d], pL[pblk*128+half*64+ql]
        const int pblk = bh * 16 + (qb - 16);
        const int ql   = wave * 16 + l16;    // local q row 0..63
        float* po = pO + ((size_t)(pblk * 2 + half)) * 4096;
#pragma unroll
        for (int dt = 0; dt < 4; dt++)
            *(float4x*)&po[ql * 64 + dt * 16 + quad * 4] = O[dt];
        if (quad == 0) pL[pblk * 128 + half * 64 + ql] = lacc[0];
        return;
    }

    // unsplit epilogue: l[q=l16] in every lane via ones-MFMA; normalize,
    // swizzled LDS transpose, store.
    float rl = 1.0f / lacc[0];
#pragma unroll
    for (int dt = 0; dt < 4; dt++) {
        uint2x o = { pk2(O[dt][0] * rl, O[dt][1] * rl),
                     pk2(O[dt][2] * rl, O[dt][3] * rl) };
        *(uint2x*)&Pl[wave][l16 * 64 + ((2 * dt + (quad >> 1)) ^ sw) * 8 + (quad & 1) * 4] = o;
    }
    const int t = qbase + l16;
#pragma unroll
    for (int cc = 0; cc < 2; cc++) {
        short8x row = *(const short8x*)&Pl[wave][l16 * 64 + ((2 * quad + cc) ^ sw) * 8];
        *(short8x*)&Y[((size_t)(b * 2048 + t)) * 1024 + h * 64 + (2 * quad + cc) * 8] = row;
    }
}

// ---------------------------------------------------------------------------
// Combine: one block per (bh, qb-16). Y rows qb*64..qb*64+63 (qb>=16):
// Y = (O_half0 + O_half1) / (l0 + l1). 512 blocks x 256 threads.
// ---------------------------------------------------------------------------
__global__ __launch_bounds__(256) void attn_combine(const float* __restrict__ pO,
                                                    const float* __restrict__ pL,
                                                    unsigned short* __restrict__ Y) {
    const int blk = blockIdx.x;            // bh*16 + (qb-16)
    const int bh = blk >> 4;
    const int qb = 16 + (blk & 15);
    const int b = bh >> 4, h = bh & 15;
    const int tid = threadIdx.x;
    const int q  = tid >> 2;               // 0..63
    const int c0 = (tid & 3) * 16;         // 0,16,32,48

    const float* p0 = pO + ((size_t)blk * 2 + 0) * 4096 + q * 64 + c0;
    const float* p1 = pO + ((size_t)blk * 2 + 1) * 4096 + q * 64 + c0;
    const float l = pL[blk * 128 + q] + pL[blk * 128 + 64 + q];
    const float rl = 1.0f / l;
    unsigned short* yp = Y + ((size_t)(b * 2048 + qb * 64 + q)) * 1024 + h * 64 + c0;
#pragma unroll
    for (int i = 0; i < 4; i++) {
        float4 a = *(const float4*)(p0 + i * 4);
        float4 c = *(const float4*)(p1 + i * 4);
        ushort4x r = { f2b((a.x + c.x) * rl), f2b((a.y + c.y) * rl),
                       f2b((a.z + c.z) * rl), f2b((a.w + c.w) * rl) };
        *(ushort4x*)(yp + i * 4) = r;
    }
}

// ---------------------------------------------------------------------------
extern "C" void kernel_launch(void* const* d_in, const int* in_sizes, int n_in,
                              void* d_out, int out_size, void* d_ws, size_t ws_size,
                              hipStream_t stream) {
    const float* x      = (const float*)d_in[0];
    const float* w_attn = (const float*)d_in[1];
    const float* b_attn = (const float*)d_in[2];
    const float* w_proj = (const float*)d_in[3];
    const float* b_proj = (const float*)d_in[4];
    float* out = (float*)d_out;

    char* ws = (char*)d_ws;
    unsigned short* xb  = (unsigned short*)(ws + (size_t)0);          // 8 MB [4096,1024]
    unsigned short* waT = (unsigned short*)(ws + (size_t)(8  << 20)); // 6 MB [3072,1024]
    unsigned short* wpT = (unsigned short*)(ws + (size_t)(14 << 20)); // 2 MB [1024,1024]
    unsigned short* QKb = (unsigned short*)(ws + (size_t)(16 << 20)); // 16 MB [4096,2048]
    unsigned short* VTb = (unsigned short*)(ws + (size_t)(32 << 20)); // 8 MB [B,H,64,2048]
    unsigned short* yb  = (unsigned short*)(ws + (size_t)(40 << 20)); // 8 MB [4096,1024]
    float*          pO  = (float*)(ws + (size_t)(48 << 20));          // 16 MB partials
    float*          pL  = (float*)(ws + (size_t)(64 << 20));          // 0.25 MB partial l

    prep<<<8192, 256, 0, stream>>>(x, xb, w_attn, waT, w_proj, wpT);

    gemm_qkv<<<dim3(24, 32), 256, 0, stream>>>(xb, waT, b_attn, QKb, VTb);

    attn_kernel<<<1536, 256, 0, stream>>>(QKb, VTb, yb, pO, pL);

    attn_combine<<<512, 256, 0, stream>>>(pO, pL, yb);

    gemm_proj<<<dim3(8, 64), 256, 0, stream>>>(yb, wpT, b_proj, out);
}

// Round 14
// 163.393 us; speedup vs baseline: 1.0412x; 1.0412x over previous
//
#include <hip/hip_runtime.h>
#include <hip/hip_bf16.h>

// B=2, T=2048, C=1024, H=16, D=64
// qkv = x@w_attn + b_attn ; causal attention ; out = y@w_proj + b_proj
// R21: revert R20 split-K (164->170: +20MB f32 partial traffic + 5th
//      launch + duplicated prologues outweighed the ~5us tail saving).
//      Base = R19 (164.0 best: LPT attn + 48KB pad + pk2t + MFMA-denom).
//      One delta: gemm_proj BK=64 -> BK=128 via TWO 64-wide panels
//      (A[2][64x64], B[2][128x64] = 48KB): 12 stage32 units balanced 3
//      per wave (was 4/8 imbalance), ONE barrier pair per 128-K -> half
//      the vmcnt(0) drains; per-panel read indexing identical to R19
//      (no new fragment math). Occupancy unchanged (grid 512 = 2/CU).

typedef __attribute__((ext_vector_type(8))) short short8x;   // 8 bf16 (A/B frag)
typedef __attribute__((ext_vector_type(4))) float float4x;   // C/D frag
typedef __attribute__((ext_vector_type(4))) unsigned short ushort4x;
typedef __attribute__((ext_vector_type(2))) unsigned int uint2x;

#define MFMA_BF16 __builtin_amdgcn_mfma_f32_16x16x32_bf16

typedef const __attribute__((address_space(1))) void gvoid_t;
typedef __attribute__((address_space(3))) void lvoid_t;
#define GLOAD_LDS16(g, l) __builtin_amdgcn_global_load_lds((gvoid_t*)(g), (lvoid_t*)(l), 16, 0, 0)

__device__ __forceinline__ unsigned short f2b(float f) {
    unsigned int u = __float_as_uint(f);
    u = (u + 0x7FFFu + ((u >> 16) & 1u)) >> 16;
    return (unsigned short)u;
}
// rounded pack (round-half-up): lo16 = bf16(a), hi16 = bf16(b). 3 VALU.
__device__ __forceinline__ unsigned int pk2(float a, float b) {
    return __builtin_amdgcn_perm(__float_as_uint(b) + 0x8000u,
                                 __float_as_uint(a) + 0x8000u, 0x07060302u);
}
// truncating pack: lo16 = trunc_bf16(a), hi16 = trunc_bf16(b). 1 VALU.
// Safe for e = exp2(S) >= 0; bias cancels in P/l normalization.
__device__ __forceinline__ unsigned int pk2t(float a, float b) {
    return __builtin_amdgcn_perm(__float_as_uint(b),
                                 __float_as_uint(a), 0x07060302u);
}

// Stage rows [w0,w0+32) of a 64-short-wide tile from global (row stride rs
// shorts) into LDS (stride 64), source-XOR-swizzled: phys chunk c of row R
// holds logical chunk c^(R&7). 4 DMA instrs, 8 rows each.
__device__ __forceinline__ void stage32(const unsigned short* g, size_t rs,
                                        short* ldst, int w0, int lane) {
    const int r8 = lane >> 3;
    const int sc = ((lane & 7) ^ r8) * 8;
#pragma unroll
    for (int q = 0; q < 4; q++) {
        GLOAD_LDS16(g + (size_t)(w0 + q * 8 + r8) * rs + sc,
                    ldst + (w0 + q * 8) * 64);
    }
}

// ---------------------------------------------------------------------------
// prep: blocks 0..4095 cast x (f32->bf16, float4); blocks 4096..8191
// transpose+cast w_attn (96 col-blocks) / w_proj (32 col-blocks).
// ---------------------------------------------------------------------------
__global__ __launch_bounds__(256) void prep(const float* __restrict__ x,
                                            unsigned short* __restrict__ xb,
                                            const float* __restrict__ wa,
                                            unsigned short* __restrict__ waT,
                                            const float* __restrict__ wp,
                                            unsigned short* __restrict__ wpT) {
    __shared__ float tile[32][33];
    const int blk = blockIdx.x;
    if (blk < 4096) {
        int i = blk * 256 + threadIdx.x;
        float4 v = ((const float4*)x)[i];
        ushort4x o = { f2b(v.x), f2b(v.y), f2b(v.z), f2b(v.w) };
        ((ushort4x*)xb)[i] = o;
        return;
    }
    int idx = blk - 4096;
    int bx = idx & 127;   // 0..127
    int by = idx >> 7;    // 0..31
    const float* in;
    unsigned short* outp;
    int cols;
    if (bx < 96) { in = wa; outp = waT; cols = 3072; }
    else         { in = wp; outp = wpT; cols = 1024; bx -= 96; }
    const int tx = threadIdx.x & 31, ty = threadIdx.x >> 5;
    const int cbase = bx * 32, rbase = by * 32;
    int c = cbase + tx;
    for (int j = 0; j < 32; j += 8)
        tile[ty + j][tx] = in[(size_t)(rbase + ty + j) * cols + c];
    __syncthreads();
    int rr = rbase + tx;
    for (int j = 0; j < 32; j += 8) {
        int cc = cbase + ty + j;
        outp[(size_t)cc * 1024 + rr] = f2b(tile[tx][ty + j]);
    }
}

// ---------------------------------------------------------------------------
// QKV GEMM main loop (R14): compile-time operand order, BK=64 single-buffer.
// SWAP=true computes C^T fragments (lane holds 4 consecutive C columns).
// ---------------------------------------------------------------------------
template <bool SWAP>
__device__ __forceinline__ void qkv_mainloop(const unsigned short* Ag,
                                             const unsigned short* Bg,
                                             short* lA, short* lB,
                                             float4x (&acc)[4][4],
                                             int wave, int lane, int wr, int wc,
                                             int quad, int l16, int sw) {
    const int K = 1024;
    for (int kk = 0; kk < K; kk += 64) {
        stage32(Ag + kk, K, lA, wave * 32, lane);
        stage32(Bg + kk, K, lB, wave * 32, lane);
        __syncthreads();

#pragma unroll
        for (int kk2 = 0; kk2 < 2; kk2++) {
            short8x a[4], b[4];
#pragma unroll
            for (int i = 0; i < 4; i++)
                a[i] = *(const short8x*)&lA[(wr * 64 + i * 16 + l16) * 64 +
                                            ((kk2 * 4 + quad) ^ sw) * 8];
#pragma unroll
            for (int j = 0; j < 4; j++)
                b[j] = *(const short8x*)&lB[(wc * 64 + j * 16 + l16) * 64 +
                                            ((kk2 * 4 + quad) ^ sw) * 8];
#pragma unroll
            for (int i = 0; i < 4; i++)
#pragma unroll
                for (int j = 0; j < 4; j++)
                    acc[i][j] = SWAP ? MFMA_BF16(b[j], a[i], acc[i][j], 0, 0, 0)
                                     : MFMA_BF16(a[i], b[j], acc[i][j], 0, 0, 0);
        }
        __syncthreads();
    }
}

// ---------------------------------------------------------------------------
// QKV GEMM: [4096,3072] = xb[4096,1024] @ waT[3072,1024]^T + b_attn
// 128x128 tile, 4 waves 2x2, BK=64, single-buffered swizzled DMA staging.
// Q/K blocks (x<16): SWAP mainloop -> packed 8B stores + float4 bias.
// V blocks: standard orientation -> VT[bh][d][t] via LDS transpose.
// ---------------------------------------------------------------------------
__global__ __launch_bounds__(256, 4) void gemm_qkv(const unsigned short* __restrict__ A,
                                                   const unsigned short* __restrict__ BT,
                                                   const float* __restrict__ bias,
                                                   unsigned short* __restrict__ QK,
                                                   unsigned short* __restrict__ VTg) {
    __shared__ union {
        struct { short A[128 * 64]; short B[128 * 64]; } s;   // 32 KB
        short vt[4][64 * 80];                                  // 40 KB
    } lds;

    const int K = 1024;
    const int lane = threadIdx.x & 63;
    const int wave = threadIdx.x >> 6;
    const int quad = lane >> 4;
    const int l16  = lane & 15;
    const int sw   = l16 & 7;

    const int rblk = blockIdx.y * 128;
    const int cblk = blockIdx.x * 128;
    const int wr = wave >> 1, wc = wave & 1;
    const bool qk = (blockIdx.x < 16);   // blocks 0..15 pure Q/K, 16..23 pure V

    float4x acc[4][4] = {};

    const unsigned short* Ag = A  + (size_t)rblk * K;
    const unsigned short* Bg = BT + (size_t)cblk * K;

    if (qk) qkv_mainloop<true >(Ag, Bg, lds.s.A, lds.s.B, acc, wave, lane, wr, wc, quad, l16, sw);
    else    qkv_mainloop<false>(Ag, Bg, lds.s.A, lds.s.B, acc, wave, lane, wr, wc, quad, l16, sw);

    const int rbase = rblk + wr * 64;
    const int cbase = cblk + wc * 64;

    if (qk) {
        // swapped layout: lane (l16,quad) reg r holds C[rbase+i*16+l16]
        //                                             [cbase+j*16+quad*4+r]
        const float sc = (blockIdx.x < 8) ? 0.18033688f : 1.0f;  // log2(e)/8 | 1
#pragma unroll
        for (int i = 0; i < 4; i++) {
            const int r = rbase + i * 16 + l16;
#pragma unroll
            for (int j = 0; j < 4; j++) {
                const int c = cbase + j * 16 + quad * 4;
                float4 bv = *(const float4*)&bias[c];
                uint2x p = { pk2((acc[i][j][0] + bv.x) * sc, (acc[i][j][1] + bv.y) * sc),
                             pk2((acc[i][j][2] + bv.z) * sc, (acc[i][j][3] + bv.w) * sc) };
                *(uint2x*)&QK[(size_t)r * 2048 + c] = p;
            }
        }
    } else {
#pragma unroll
        for (int i = 0; i < 4; i++) {
#pragma unroll
            for (int j = 0; j < 4; j++) {
                int c = cbase + j * 16 + l16;
                float bv = bias[c];
                uint2x p = { pk2(acc[i][j][0] + bv, acc[i][j][1] + bv),
                             pk2(acc[i][j][2] + bv, acc[i][j][3] + bv) };
                *(uint2x*)&lds.vt[wave][(j * 16 + l16) * 80 + i * 16 + quad * 4] = p;
            }
        }
        const int h   = (cbase - 2048) >> 6;
        const int hb  = (rbase >> 11) * 16 + h;
        const int tb0 = rbase & 2047;
#pragma unroll
        for (int p = 0; p < 8; p++) {
            int dd   = p * 8 + (lane >> 3);
            int toff = (lane & 7) * 8;
            short8x vv = *(const short8x*)&lds.vt[wave][dd * 80 + toff];
            *(short8x*)&VTg[((size_t)(hb * 64 + dd)) * 2048 + tb0 + toff] = vv;
        }
    }
}

// ---------------------------------------------------------------------------
// Proj GEMM: out[4096,1024] = yb @ wpT^T + b_proj (fp32).
// 64(M) x 128(N) tile, 4 waves side-by-side in N (64x32 each).
// R21: BK=128 via two 64-wide panels (A[2][64x64], B[2][128x64] = 48 KB);
// 12 stage32 units balanced 3/wave; ONE barrier pair per 128-K (8 iters,
// was 16) -> half the vmcnt(0) drains. Per-panel reads identical to R19.
// grid (8, 64) = 512 blocks = 2/CU.
// ---------------------------------------------------------------------------
__global__ __launch_bounds__(256) void gemm_proj(const unsigned short* __restrict__ A,
                                                 const unsigned short* __restrict__ BT,
                                                 const float* __restrict__ bias,
                                                 float* __restrict__ out) {
    __shared__ struct { short A[2][64 * 64]; short B[2][128 * 64]; } lds;  // 48 KB

    const int K = 1024, N = 1024;
    const int lane = threadIdx.x & 63;
    const int wave = threadIdx.x >> 6;
    const int quad = lane >> 4;
    const int l16  = lane & 15;
    const int sw   = l16 & 7;

    const int rblk = blockIdx.y * 64;
    const int cblk = blockIdx.x * 128;

    float4x acc[4][2] = {};

    const unsigned short* Ag = A  + (size_t)rblk * K;
    const unsigned short* Bg = BT + (size_t)cblk * K;

    for (int kk = 0; kk < K; kk += 128) {
        // 12 stage32 units: u<4 -> A panel u>>1 rows (u&1)*32;
        // u>=4 -> B panel (u-4)>>2 rows ((u-4)&3)*32. Wave w takes 3w..3w+2.
#pragma unroll
        for (int t = 0; t < 3; t++) {
            const int u = wave * 3 + t;
            if (u < 4) {
                stage32(Ag + kk + (u >> 1) * 64, K, lds.A[u >> 1], (u & 1) * 32, lane);
            } else {
                const int v = u - 4;
                stage32(Bg + kk + (v >> 2) * 64, K, lds.B[v >> 2], (v & 3) * 32, lane);
            }
        }
        __syncthreads();

#pragma unroll
        for (int kp = 0; kp < 2; kp++) {
#pragma unroll
            for (int kk2 = 0; kk2 < 2; kk2++) {
                short8x b[2];
#pragma unroll
                for (int j = 0; j < 2; j++)
                    b[j] = *(const short8x*)&lds.B[kp][(wave * 32 + j * 16 + l16) * 64 +
                                                       ((kk2 * 4 + quad) ^ sw) * 8];
#pragma unroll
                for (int i = 0; i < 4; i++) {
                    short8x a = *(const short8x*)&lds.A[kp][(i * 16 + l16) * 64 +
                                                            ((kk2 * 4 + quad) ^ sw) * 8];
#pragma unroll
                    for (int j = 0; j < 2; j++)
                        acc[i][j] = MFMA_BF16(a, b[j], acc[i][j], 0, 0, 0);
                }
            }
        }
        __syncthreads();
    }

#pragma unroll
    for (int j = 0; j < 2; j++) {
        const int c = cblk + wave * 32 + j * 16 + l16;
        const float bv = bias[c];
#pragma unroll
        for (int i = 0; i < 4; i++) {
#pragma unroll
            for (int reg = 0; reg < 4; reg++) {
                int r = rblk + i * 16 + quad * 4 + reg;
                out[(size_t)r * N + c] = acc[i][j][reg] + bv;
            }
        }
    }
}

// ---------------------------------------------------------------------------
// Flash attention (causal), S^T = K*Q^T, static-max base-2 softmax.
// QK [4096][2048] bf16 (Q pre-scaled log2e/8 | K), VT [bh][64][2048] bf16,
// Y [4096][1024] bf16. Block = 64 q-rows, 4 waves x 16 rows; 64-key tiles
// double-buffered in LDS via swizzled DMA (waves 0-1 K, 2-3 V).
// R19: LDS padded to 48 KB (Pl[4][2048], only [0..1023] used) -> 3 blk/CU
// -> 256-block backfill pool; LPT dispatch (qb = 31-(bid>>5): longest
// first; bh = bid&31 keeps 4-bh/XCD L2 locality).
// R14: softmax denominator via MFMA(ones, bp).
// R18: inner P-pack via truncating pk2t.
// ---------------------------------------------------------------------------
__global__ __launch_bounds__(256) void attn_kernel(const unsigned short* __restrict__ QK,
                                                   const unsigned short* __restrict__ VT,
                                                   unsigned short* __restrict__ Y) {
    __shared__ __attribute__((aligned(16))) short Kl[2][64 * 64];  // 16 KB
    __shared__ __attribute__((aligned(16))) short Vl[2][64 * 64];  // 16 KB
    __shared__ __attribute__((aligned(16))) short Pl[4][2048];     // 16 KB (8 used; pad->48KB)

    const int tid  = threadIdx.x;
    const int lane = tid & 63;
    const int wave = tid >> 6;
    const int quad = lane >> 4;
    const int l16  = lane & 15;
    const int sw   = l16 & 7;

    // LPT dispatch map: longest blocks (qb=31) get lowest bids -> start
    // first; shortest blocks dispatched last, backfilling freed slots.
    const int bid = blockIdx.x;
    const int qb  = 31 - (bid >> 5);
    const int bh  = bid & 31;
    const int b = bh >> 4, h = bh & 15;

    const unsigned short* Qp = QK + ((size_t)b * 2048) * 2048 + h * 64;
    const unsigned short* Kp = Qp + 1024;
    const unsigned short* Vp = VT + (size_t)bh * 64 * 2048;

    const int qbase = qb * 64 + wave * 16;           // 16 q-rows per wave
    const int ntb   = qb + 1;                        // 64-key tiles

    short8x aq[2];
#pragma unroll
    for (int kk = 0; kk < 2; kk++)
        aq[kk] = *(const short8x*)(Qp + (size_t)(qbase + l16) * 2048 + kk * 32 + quad * 8);

    // bf16 1.0 fragment for the denominator MFMA
    const short ONE = (short)0x3F80;
    const short8x ones = { ONE, ONE, ONE, ONE, ONE, ONE, ONE, ONE };

    // prologue: stage tile 0 into buf 0
    if (wave < 2) stage32(Kp, 2048, Kl[0], wave * 32, lane);
    else          stage32(Vp, 2048, Vl[0], (wave - 2) * 32, lane);
    __syncthreads();

    float4x lacc = {};
    float4x O[4] = {};

    for (int it = 0; it < ntb; it++) {
        const int kb = it * 64;
        const short* Kc = Kl[it & 1];
        const short* Vc = Vl[it & 1];

        if (it + 1 < ntb) {
            const int kb2 = kb + 64;
            if (wave < 2) stage32(Kp + (size_t)kb2 * 2048, 2048, Kl[(it + 1) & 1], wave * 32, lane);
            else          stage32(Vp + kb2, 2048, Vl[(it + 1) & 1], (wave - 2) * 32, lane);
        }

        float4x S[4];
#pragma unroll
        for (int t = 0; t < 4; t++) {
            short8x kf0 = *(const short8x*)&Kc[(t * 16 + l16) * 64 + ((quad) ^ sw) * 8];
            short8x kf1 = *(const short8x*)&Kc[(t * 16 + l16) * 64 + ((4 + quad) ^ sw) * 8];
            S[t] = (float4x){0.f, 0.f, 0.f, 0.f};
            S[t] = MFMA_BF16(kf0, aq[0], S[t], 0, 0, 0);
            S[t] = MFMA_BF16(kf1, aq[1], S[t], 0, 0, 0);
        }

        if (kb + 64 > qbase) {
            int q = qbase + l16;
#pragma unroll
            for (int t = 0; t < 4; t++)
#pragma unroll
                for (int reg = 0; reg < 4; reg++)
                    if (kb + t * 16 + quad * 4 + reg > q) S[t][reg] = -1e38f;
        }

#pragma unroll
        for (int t = 0; t < 4; t++) {
            float e0 = __builtin_amdgcn_exp2f(S[t][0]);
            float e1 = __builtin_amdgcn_exp2f(S[t][1]);
            float e2 = __builtin_amdgcn_exp2f(S[t][2]);
            float e3 = __builtin_amdgcn_exp2f(S[t][3]);
            uint2x p = { pk2t(e0, e1), pk2t(e2, e3) };
            *(uint2x*)&Pl[wave][l16 * 64 + ((2 * t + (quad >> 1)) ^ sw) * 8 + (quad & 1) * 4] = p;
        }

#pragma unroll
        for (int kc = 0; kc < 2; kc++) {
            short8x bp = *(const short8x*)&Pl[wave][l16 * 64 + ((4 * kc + quad) ^ sw) * 8];
            lacc = MFMA_BF16(ones, bp, lacc, 0, 0, 0);
#pragma unroll
            for (int dt = 0; dt < 4; dt++) {
                short8x vf = *(const short8x*)&Vc[(dt * 16 + l16) * 64 + ((kc * 4 + quad) ^ sw) * 8];
                O[dt] = MFMA_BF16(vf, bp, O[dt], 0, 0, 0);
            }
        }
        __syncthreads();
    }

    // epilogue: l[q=l16] already in every lane via ones-MFMA; normalize,
    // swizzled LDS transpose, store.
    float rl = 1.0f / lacc[0];
#pragma unroll
    for (int dt = 0; dt < 4; dt++) {
        uint2x o = { pk2(O[dt][0] * rl, O[dt][1] * rl),
                     pk2(O[dt][2] * rl, O[dt][3] * rl) };
        *(uint2x*)&Pl[wave][l16 * 64 + ((2 * dt + (quad >> 1)) ^ sw) * 8 + (quad & 1) * 4] = o;
    }
    const int t = qbase + l16;
#pragma unroll
    for (int cc = 0; cc < 2; cc++) {
        short8x row = *(const short8x*)&Pl[wave][l16 * 64 + ((2 * quad + cc) ^ sw) * 8];
        *(short8x*)&Y[((size_t)(b * 2048 + t)) * 1024 + h * 64 + (2 * quad + cc) * 8] = row;
    }
}

// ---------------------------------------------------------------------------
extern "C" void kernel_launch(void* const* d_in, const int* in_sizes, int n_in,
                              void* d_out, int out_size, void* d_ws, size_t ws_size,
                              hipStream_t stream) {
    const float* x      = (const float*)d_in[0];
    const float* w_attn = (const float*)d_in[1];
    const float* b_attn = (const float*)d_in[2];
    const float* w_proj = (const float*)d_in[3];
    const float* b_proj = (const float*)d_in[4];
    float* out = (float*)d_out;

    char* ws = (char*)d_ws;
    unsigned short* xb  = (unsigned short*)(ws + (size_t)0);          // 8 MB [4096,1024]
    unsigned short* waT = (unsigned short*)(ws + (size_t)(8  << 20)); // 6 MB [3072,1024]
    unsigned short* wpT = (unsigned short*)(ws + (size_t)(14 << 20)); // 2 MB [1024,1024]
    unsigned short* QKb = (unsigned short*)(ws + (size_t)(16 << 20)); // 16 MB [4096,2048]
    unsigned short* VTb = (unsigned short*)(ws + (size_t)(32 << 20)); // 8 MB [B,H,64,2048]
    unsigned short* yb  = (unsigned short*)(ws + (size_t)(40 << 20)); // 8 MB [4096,1024]

    prep<<<8192, 256, 0, stream>>>(x, xb, w_attn, waT, w_proj, wpT);

    gemm_qkv<<<dim3(24, 32), 256, 0, stream>>>(xb, waT, b_attn, QKb, VTb);

    attn_kernel<<<1024, 256, 0, stream>>>(QKb, VTb, yb);

    gemm_proj<<<dim3(8, 64), 256, 0, stream>>>(yb, wpT, b_proj, out);
}